// Round 5
// baseline (438.709 us; speedup 1.0000x reference)
//
#include <hip/hip_runtime.h>

// out[o,c,y,x] = sum_{i',j<31} s[c,y+i'-15,x+j-15] * w[o,c,i',j] + bias[c]
// via v_mfma_f32_16x16x32_f16 with the Y-shift packed into m:
//   m = 8*s + o (s in {0,1}), n = x (16 cols), k = j (32, j=31 zero-pad)
//   A_i[8s+o][k] = w[o,c,i-s,k]  (i = i'+s, loop i = 0..31; zero outside range)
//   B_i,p[k][n]  = s[y0+2p+i-15, x0+xw+n+k-15]   -- ONE signal row, wave-uniform
// Lane (n,kg) B-fragment = 8 consecutive f16 at column E = xw+n+8kg of that row
// -> dual-parity LDS copies make it 4 aligned dwords for any E.
// Rows recur across i (row = i+2p): 16-slot f16x8 register cache, ONE new
// ds_read_b128 per iteration. launch_bounds(256,3) gives the allocator ~170
// regs so the 64-VGPR cache stays resident (at (256,4)/128 it was rematerialized
// from LDS -> 8 b128/iter -> LDS-pipe-bound at 175 us).

typedef _Float16 f16x8 __attribute__((ext_vector_type(8)));
typedef float    f32x4 __attribute__((ext_vector_type(4)));

#define TY   16          // output rows per block
#define TXB  64          // output cols per block (16 per wave)
#define SR   48          // 46 real tile rows + 2 garbage rows (unguarded refill)
#define SDW  48          // dwords per parity copy per row (96 f16)
#define SROW 97          // row stride dwords: [copy0 48][copy1 48][pad 1]

// A-fragment table: [c][i(33, padded)][lane][4dw]; lane l reads 16B at byte l*16
__device__ unsigned int g_wA[8 * 33 * 256];

__global__ void wpack(const float* __restrict__ wgt) {
  int t = blockIdx.x * 256 + threadIdx.x;
  if (t >= 8 * 33 * 256) return;
  const int d    = t & 3;
  const int lane = (t >> 2) & 63;
  const int r    = t >> 8;
  const int i    = r % 33;
  const int c    = r / 33;
  const int m  = lane & 15;
  const int kg = lane >> 4;
  const int o  = m & 7;
  const int s  = m >> 3;
  const int ip = i - s;                 // weight row i' = i - s
  const int k0 = kg * 8 + 2 * d;        // k = j
  float w0 = 0.f, w1 = 0.f;
  if ((unsigned)ip < 31u) {
    const float* wsrc = wgt + ((o * 8 + c) * 31 + ip) * 31;
    if (k0 < 31)     w0 = wsrc[k0];
    if (k0 + 1 < 31) w1 = wsrc[k0 + 1];
  }
  union { _Float16 h[2]; unsigned int u; } p;
  p.h[0] = (_Float16)w0; p.h[1] = (_Float16)w1;
  g_wA[t] = p.u;
}

__global__ __launch_bounds__(256, 3)
void conv_mfma4(const float* __restrict__ sig,
                const float* __restrict__ bias,
                float* __restrict__ out) {
  __shared__ unsigned int ldss[SR * SROW];   // 18.6 KB

  const int tid = threadIdx.x;
  const int c  = blockIdx.z;
  const int x0 = blockIdx.x * TXB;
  const int y0 = blockIdx.y * TY;

  // ---- stage tile: rows y0-15..y0+30 (46), elements x0-15..x0+80, dual parity ----
  const float* sc = sig + c * (1024 * 1024);
  for (int f = tid; f < 46 * SDW; f += 256) {
    const int r = f / SDW;
    const int d = f - r * SDW;
    const int gy = y0 + r - 15;
    const int gx = x0 + 2 * d - 15;
    float s0 = 0.f, s1 = 0.f, s2 = 0.f;
    if ((unsigned)gy < 1024u) {
      const float* srcr = sc + gy * 1024;
      if ((unsigned)gx < 1024u)       s0 = srcr[gx];
      if ((unsigned)(gx + 1) < 1024u) s1 = srcr[gx + 1];
      if ((unsigned)(gx + 2) < 1024u) s2 = srcr[gx + 2];
    }
    union { _Float16 h[2]; unsigned int u; } p0, p1;
    p0.h[0] = (_Float16)s0; p0.h[1] = (_Float16)s1;   // copy0: (e2d, e2d+1)
    p1.h[0] = (_Float16)s1; p1.h[1] = (_Float16)s2;   // copy1: (e2d+1, e2d+2)
    ldss[r * SROW + d]       = p0.u;
    ldss[r * SROW + SDW + d] = p1.u;
  }
  __syncthreads();

  const int lane = tid & 63;
  const int wv   = tid >> 6;
  const int n    = lane & 15;       // MFMA col -> x offset
  const int kg   = lane >> 4;       // k-group
  const int xw   = wv * 16;

  // per-lane fixed B-window base: elements E..E+7 of a row
  const int E = xw + n + 8 * kg;
  const unsigned int* lbase = ldss + (E & 1) * SDW + (E >> 1);

  f32x4 acc[8];
  #pragma unroll
  for (int p = 0; p < 8; ++p) acc[p] = (f32x4){0.f, 0.f, 0.f, 0.f};

  // B register cache: slot (row & 15); preload rows 0..15
  f16x8 Bc[16];
  #pragma unroll
  for (int r = 0; r < 16; ++r)
    Bc[r] = __builtin_bit_cast(f16x8, *(const uint4*)(lbase + r * SROW));

  const uint4* wq = (const uint4*)g_wA + (size_t)c * (33 * 64) + lane;
  uint4 aq = wq[0];

  #pragma unroll
  for (int i = 0; i < 32; ++i) {
    const f16x8 af = __builtin_bit_cast(f16x8, aq);
    aq = wq[(i + 1) * 64];                                   // padded: i=31 -> slot 32
    // refill value: row i+16 (rows 46/47 are garbage, never consumed)
    const f16x8 nb = __builtin_bit_cast(f16x8, *(const uint4*)(lbase + (i + 16) * SROW));
    // p = 0 consumes slot i&15 (row i), freed for refill afterwards
    acc[0] = __builtin_amdgcn_mfma_f32_16x16x32_f16(af, Bc[i & 15], acc[0], 0, 0, 0);
    #pragma unroll
    for (int p = 1; p < 8; ++p)
      acc[p] = __builtin_amdgcn_mfma_f32_16x16x32_f16(af, Bc[(i + 2 * p) & 15], acc[p], 0, 0, 0);
    Bc[i & 15] = nb;
  }

  // ---- epilogue ----
  // D: col = lane&15 = n -> x; row m = 4kg + r = 8s + o -> s = kg>>1, o = (kg&1)*4 + r
  const float bv = bias[c];
  const int sh  = kg >> 1;
  const int ob  = (kg & 1) * 4;
  const int xs  = x0 + xw + n;
  #pragma unroll
  for (int p = 0; p < 8; ++p) {
    const int y = y0 + 2 * p + sh;
    #pragma unroll
    for (int r = 0; r < 4; ++r) {
      const int o = ob + r;
      out[(((size_t)(o * 8 + c) * 1024 + y) * 1024) + xs] = acc[p][r] + bv;
    }
  }
}

extern "C" void kernel_launch(void* const* d_in, const int* in_sizes, int n_in,
                              void* d_out, int out_size, void* d_ws, size_t ws_size,
                              hipStream_t stream) {
  const float* sig  = (const float*)d_in[0];   // (1,8,1024,1024) fp32
  const float* wgt  = (const float*)d_in[1];   // (8,8,31,31) fp32
  const float* bias = (const float*)d_in[2];   // (8,) fp32
  float* out = (float*)d_out;                  // (8,8,1024,1024) fp32

  wpack<<<(8 * 33 * 256 + 255) / 256, 256, 0, stream>>>(wgt);
  dim3 grid(1024 / TXB, 1024 / TY, 8);
  conv_mfma4<<<grid, 256, 0, stream>>>(sig, bias, out);
}